// Round 1
// baseline (419.594 us; speedup 1.0000x reference)
//
#include <hip/hip_runtime.h>
#include <stdint.h>

#define BB 8
#define TT 256
#define DD 256
#define NSTEP 12
#define NNEG 100
// rows of "partial": 255 t-slots x B x NSTEP (invalid t writes 0)
#define NPART (255 * BB * NSTEP)

// ---------------- Threefry2x32 (JAX-compatible) ----------------
__device__ __forceinline__ void tf2x32(uint32_t k0, uint32_t k1,
                                       uint32_t x0, uint32_t x1,
                                       uint32_t &y0, uint32_t &y1) {
  const uint32_t ks2 = k0 ^ k1 ^ 0x1BD11BDAu;
  x0 += k0; x1 += k1;
#define TF_R(r) { x0 += x1; x1 = (x1 << (r)) | (x1 >> (32 - (r))); x1 ^= x0; }
  TF_R(13) TF_R(15) TF_R(26) TF_R(6)
  x0 += k1; x1 += ks2 + 1u;
  TF_R(17) TF_R(29) TF_R(16) TF_R(24)
  x0 += ks2; x1 += k0 + 2u;
  TF_R(13) TF_R(15) TF_R(26) TF_R(6)
  x0 += k0; x1 += k1 + 3u;
  TF_R(17) TF_R(29) TF_R(16) TF_R(24)
  x0 += k1; x1 += ks2 + 4u;
  TF_R(13) TF_R(15) TF_R(26) TF_R(6)
  x0 += ks2; x1 += k0 + 5u;
#undef TF_R
  y0 = x0; y1 = x1;
}

// Per-step derived keys: fold_in(key(1234), step) then split -> k1,k2
__global__ void step_keys_kernel(uint4* __restrict__ keys) {
  int tid = threadIdx.x;
  if (tid < NSTEP) {
    uint32_t a, b;
    tf2x32(0u, 1234u, 0u, (uint32_t)(tid + 1), a, b);   // fold_in
    uint32_t h1a, h1b, h2a, h2b;
    tf2x32(a, b, 0u, 2u, h1a, h1b);                     // split pair (0,2)
    tf2x32(a, b, 1u, 3u, h2a, h2b);                     // split pair (1,3)
    keys[tid] = make_uint4(h1a, h2a, h1b, h2b);         // k1=(x,y) k2=(z,w)
  }
}

// ---------------- normalize targets: tn = l2norm(targets) ----------------
__global__ __launch_bounds__(256) void tnorm_kernel(const float* __restrict__ tgt,
                                                    float* __restrict__ tn) {
  const int row  = blockIdx.x * 4 + (threadIdx.x >> 6);
  const int lane = threadIdx.x & 63;
  float4 v = ((const float4*)(tgt + (size_t)row * DD))[lane];
  float ss = v.x*v.x + v.y*v.y + v.z*v.z + v.w*v.w;
#pragma unroll
  for (int off = 1; off < 64; off <<= 1) ss += __shfl_xor(ss, off, 64);
  float scale = 1.0f / fmaxf(sqrtf(ss), 1e-12f);
  v.x *= scale; v.y *= scale; v.z *= scale; v.w *= scale;
  ((float4*)(tn + (size_t)row * DD))[lane] = v;
}

// ---------------- query GEMM + bias + row l2norm, all 12 steps ----------------
// grid: 12 steps x 64 tiles (32 rows each). block 256 = 4 waves.
// wave rg owns rows rg*8..rg*8+7; lane ce owns cols ce*4..ce*4+3.
__global__ __launch_bounds__(256) void qgemm_kernel(const float* __restrict__ ctx,
                                                    const float* __restrict__ W,
                                                    const float* __restrict__ bias,
                                                    float* __restrict__ qn) {
  const int s    = blockIdx.x >> 6;
  const int tile = blockIdx.x & 63;
  const int tid  = threadIdx.x;
  const int rg   = tid >> 6;
  const int ce   = tid & 63;
  __shared__ float As[32][DD];
  const int m0 = tile * 32;
  {
    const float4* src = (const float4*)(ctx + (size_t)m0 * DD);
    float4* dst = (float4*)&As[0][0];
#pragma unroll
    for (int i = 0; i < 8; ++i) dst[tid + i * 256] = src[tid + i * 256];
  }
  __syncthreads();
  const float* Wp = W + (size_t)s * DD * DD + (size_t)(ce * 4) * DD;
  float acc[8][4];
#pragma unroll
  for (int i = 0; i < 8; ++i)
#pragma unroll
    for (int j = 0; j < 4; ++j) acc[i][j] = 0.f;

  for (int d4 = 0; d4 < 64; ++d4) {
    const float4 w0 = *(const float4*)(Wp + 0 * DD + d4 * 4);
    const float4 w1 = *(const float4*)(Wp + 1 * DD + d4 * 4);
    const float4 w2 = *(const float4*)(Wp + 2 * DD + d4 * 4);
    const float4 w3 = *(const float4*)(Wp + 3 * DD + d4 * 4);
#pragma unroll
    for (int i = 0; i < 8; ++i) {
      const float4 a = *(const float4*)&As[rg * 8 + i][d4 * 4];
      acc[i][0] += a.x * w0.x + a.y * w0.y + a.z * w0.z + a.w * w0.w;
      acc[i][1] += a.x * w1.x + a.y * w1.y + a.z * w1.z + a.w * w1.w;
      acc[i][2] += a.x * w2.x + a.y * w2.y + a.z * w2.z + a.w * w2.w;
      acc[i][3] += a.x * w3.x + a.y * w3.y + a.z * w3.z + a.w * w3.w;
    }
  }
  const float4 bv = *(const float4*)(bias + (size_t)s * DD + ce * 4);
#pragma unroll
  for (int i = 0; i < 8; ++i) {
    acc[i][0] += bv.x; acc[i][1] += bv.y; acc[i][2] += bv.z; acc[i][3] += bv.w;
    float ss = acc[i][0]*acc[i][0] + acc[i][1]*acc[i][1]
             + acc[i][2]*acc[i][2] + acc[i][3]*acc[i][3];
#pragma unroll
    for (int off = 1; off < 64; off <<= 1) ss += __shfl_xor(ss, off, 64);
    const float scale = 1.0f / fmaxf(sqrtf(ss), 1e-12f);
    const int m = m0 + rg * 8 + i;
    float4 o;
    o.x = acc[i][0] * scale; o.y = acc[i][1] * scale;
    o.z = acc[i][2] * scale; o.w = acc[i][3] * scale;
    *(float4*)(qn + (((size_t)s * (BB * TT)) + m) * DD + ce * 4) = o;
  }
}

// ---------------- scoring: 101 gathered dots + log-softmax per (s,b,t) ----------------
__global__ __launch_bounds__(256) void score_kernel(const float* __restrict__ qn,
                                                    const float* __restrict__ tn,
                                                    const uint4* __restrict__ keys,
                                                    float* __restrict__ partial) {
  const int t   = blockIdx.x;           // 0..254
  const int b   = blockIdx.y;           // 0..7
  const int si  = blockIdx.z;           // 0..11
  const int step = si + 1;
  const int T2   = TT - step;
  const int lin  = (si * BB + b) * 255 + t;
  const int tid  = threadIdx.x;
  if (t >= T2) { if (tid == 0) partial[lin] = 0.f; return; }

  __shared__ float qs[DD];
  __shared__ float logit[NNEG + 1];
  __shared__ int   rowIdx[NNEG + 1];

  qs[tid] = qn[(((size_t)si * (BB * TT)) + b * TT + t) * DD + tid];

  if (tid < NNEG) {
    const uint4 kk = keys[si];
    const uint32_t span = (uint32_t)(BB * T2);
    const uint32_t j = (uint32_t)((b * T2 + t) * NNEG + tid);
    uint32_t h0, h1, l0, l1;
    tf2x32(kk.x, kk.y, 0u, j, h0, h1);   // higher_bits (k1)
    tf2x32(kk.z, kk.w, 0u, j, l0, l1);   // lower_bits  (k2)
    uint32_t mult = 65536u % span;
    mult = (mult * mult) % span;
    uint32_t off = ((h0 % span) * mult + (l0 % span)) % span;
    const uint32_t bb = off / (uint32_t)T2;
    const uint32_t tt = off - bb * (uint32_t)T2;
    rowIdx[tid + 1] = (int)(bb * TT + tt + (uint32_t)step);
  } else if (tid == NNEG) {
    rowIdx[0] = b * TT + t + step;       // positive row
  }
  __syncthreads();

  const int wave = tid >> 6, lane = tid & 63;
  const float4 q4 = ((const float4*)qs)[lane];
  for (int k = wave; k <= NNEG; k += 4) {
    const float4 p = ((const float4*)(tn + (size_t)rowIdx[k] * DD))[lane];
    float d = q4.x * p.x + q4.y * p.y + q4.z * p.z + q4.w * p.w;
#pragma unroll
    for (int off = 1; off < 64; off <<= 1) d += __shfl_xor(d, off, 64);
    if (lane == 0) logit[k] = d * 10.0f;   // 1/TEMP
  }
  __syncthreads();

  if (wave == 0) {
    const float a = logit[lane];                       // lane 0 holds logit[0]
    const float c = (lane + 64 <= NNEG) ? logit[lane + 64] : -1e30f;
    float m = fmaxf(a, c);
#pragma unroll
    for (int off = 1; off < 64; off <<= 1) m = fmaxf(m, __shfl_xor(m, off, 64));
    float e = __expf(a - m) + ((lane + 64 <= NNEG) ? __expf(c - m) : 0.f);
#pragma unroll
    for (int off = 1; off < 64; off <<= 1) e += __shfl_xor(e, off, 64);
    if (lane == 0) {
      const float lse = m + logf(e);
      partial[lin] = (lse - a) / (12.0f * (float)(BB * T2));
    }
  }
}

// ---------------- final reduction ----------------
__global__ __launch_bounds__(256) void final_sum_kernel(const float* __restrict__ partial,
                                                        float* __restrict__ out) {
  __shared__ float wsum[4];
  const int tid = threadIdx.x;
  float s = 0.f;
  for (int i = tid; i < NPART; i += 256) s += partial[i];
#pragma unroll
  for (int off = 1; off < 64; off <<= 1) s += __shfl_xor(s, off, 64);
  if ((tid & 63) == 0) wsum[tid >> 6] = s;
  __syncthreads();
  if (tid == 0) out[0] = wsum[0] + wsum[1] + wsum[2] + wsum[3];
}

extern "C" void kernel_launch(void* const* d_in, const int* in_sizes, int n_in,
                              void* d_out, int out_size, void* d_ws, size_t ws_size,
                              hipStream_t stream) {
  const float* ctx  = (const float*)d_in[0];
  const float* tgt  = (const float*)d_in[1];
  const float* W    = (const float*)d_in[2];
  const float* bias = (const float*)d_in[3];
  float* out = (float*)d_out;

  float* tn = (float*)d_ws;                                  // 2048*256 f32
  float* qn = tn + (size_t)BB * TT * DD;                     // 12*2048*256 f32
  uint4* keys = (uint4*)(qn + (size_t)NSTEP * BB * TT * DD); // 12 * uint4
  float* partial = (float*)(keys + NSTEP);                   // NPART f32

  hipLaunchKernelGGL(step_keys_kernel, dim3(1), dim3(64), 0, stream, keys);
  hipLaunchKernelGGL(tnorm_kernel, dim3((BB * TT) / 4), dim3(256), 0, stream, tgt, tn);
  hipLaunchKernelGGL(qgemm_kernel, dim3(NSTEP * 64), dim3(256), 0, stream, ctx, W, bias, qn);
  hipLaunchKernelGGL(score_kernel, dim3(255, BB, NSTEP), dim3(256), 0, stream,
                     qn, tn, keys, partial);
  hipLaunchKernelGGL(final_sum_kernel, dim3(1), dim3(256), 0, stream, partial, out);
}

// Round 2
// 258.511 us; speedup vs baseline: 1.6231x; 1.6231x over previous
//
#include <hip/hip_runtime.h>
#include <stdint.h>

#define BB 8
#define TT 256
#define DD 256
#define NSTEP 12
#define NNEG 100
#define NPART (255 * BB * NSTEP)

typedef _Float16 h2 __attribute__((ext_vector_type(2)));

#if __has_builtin(__builtin_amdgcn_fdot2)
__device__ __forceinline__ float fdot2(h2 a, h2 b, float c) {
  return __builtin_amdgcn_fdot2(a, b, c, false);
}
#else
__device__ __forceinline__ float fdot2(h2 a, h2 b, float c) {
  return c + (float)a.x * (float)b.x + (float)a.y * (float)b.y;
}
#endif

union V16 { uint4 u; h2 h[4]; };

// ---------------- Threefry2x32 (JAX-compatible) ----------------
__device__ __forceinline__ void tf2x32(uint32_t k0, uint32_t k1,
                                       uint32_t x0, uint32_t x1,
                                       uint32_t &y0, uint32_t &y1) {
  const uint32_t ks2 = k0 ^ k1 ^ 0x1BD11BDAu;
  x0 += k0; x1 += k1;
#define TF_R(r) { x0 += x1; x1 = (x1 << (r)) | (x1 >> (32 - (r))); x1 ^= x0; }
  TF_R(13) TF_R(15) TF_R(26) TF_R(6)
  x0 += k1; x1 += ks2 + 1u;
  TF_R(17) TF_R(29) TF_R(16) TF_R(24)
  x0 += ks2; x1 += k0 + 2u;
  TF_R(13) TF_R(15) TF_R(26) TF_R(6)
  x0 += k0; x1 += k1 + 3u;
  TF_R(17) TF_R(29) TF_R(16) TF_R(24)
  x0 += k1; x1 += ks2 + 4u;
  TF_R(13) TF_R(15) TF_R(26) TF_R(6)
  x0 += ks2; x1 += k0 + 5u;
#undef TF_R
  y0 = x0; y1 = x1;
}

// ------------- normalize targets -> f16, plus per-step keys -------------
__global__ __launch_bounds__(256) void tnorm_keys_kernel(const float* __restrict__ tgt,
                                                         _Float16* __restrict__ tnh,
                                                         uint4* __restrict__ keys) {
  if (blockIdx.x == 0 && threadIdx.x < NSTEP) {
    const int s = threadIdx.x;
    uint32_t a, b;
    tf2x32(0u, 1234u, 0u, (uint32_t)(s + 1), a, b);     // fold_in(key(1234), step)
    uint32_t h1a, h1b, h2a, h2b;
    tf2x32(a, b, 0u, 2u, h1a, h1b);                     // split -> k1
    tf2x32(a, b, 1u, 3u, h2a, h2b);                     // split -> k2
    keys[s] = make_uint4(h1a, h2a, h1b, h2b);
  }
  const int row  = blockIdx.x * 4 + (threadIdx.x >> 6);
  const int lane = threadIdx.x & 63;
  float4 v = ((const float4*)(tgt + (size_t)row * DD))[lane];
  float ss = v.x*v.x + v.y*v.y + v.z*v.z + v.w*v.w;
#pragma unroll
  for (int off = 1; off < 64; off <<= 1) ss += __shfl_xor(ss, off, 64);
  const float scale = 1.0f / fmaxf(sqrtf(ss), 1e-12f);
  union { _Float16 h[4]; uint2 u; } o;
  o.h[0] = (_Float16)(v.x * scale); o.h[1] = (_Float16)(v.y * scale);
  o.h[2] = (_Float16)(v.z * scale); o.h[3] = (_Float16)(v.w * scale);
  ((uint2*)(tnh + (size_t)row * DD))[lane] = o.u;
}

// ------------- negative-index generation (threefry + mod) -------------
// grid (100, B, NSTEP), block 256: covers t*100+k for t in [0,255), k in [0,100)
__global__ __launch_bounds__(256) void idx_gen_kernel(const uint4* __restrict__ keys,
                                                      int* __restrict__ idx) {
  const int si = blockIdx.z;
  const int b  = blockIdx.y;
  const int lin = blockIdx.x * 256 + threadIdx.x;
  if (lin >= 255 * NNEG) return;
  const int t = lin / NNEG;
  const int k = lin - t * NNEG;
  const int step = si + 1;
  const int T2 = TT - step;
  if (t >= T2) return;
  const uint4 kk = keys[si];
  const uint32_t span = (uint32_t)(BB * T2);
  const uint32_t j = (uint32_t)((b * T2 + t) * NNEG + k);
  uint32_t h0, h1, l0, l1;
  tf2x32(kk.x, kk.y, 0u, j, h0, h1);
  tf2x32(kk.z, kk.w, 0u, j, l0, l1);
  uint32_t mult = 65536u % span;
  mult = (mult * mult) % span;
  const uint32_t off = ((h0 % span) * mult + (l0 % span)) % span;
  const uint32_t bb = off / (uint32_t)T2;
  const uint32_t tt = off - bb * (uint32_t)T2;
  idx[((si * BB + b) * 255 + t) * NNEG + k] = (int)(bb * TT + tt + (uint32_t)step);
}

// ------------- query GEMM + bias + l2norm -> f16, all steps -------------
__global__ __launch_bounds__(256) void qgemm_kernel(const float* __restrict__ ctx,
                                                    const float* __restrict__ W,
                                                    const float* __restrict__ bias,
                                                    _Float16* __restrict__ qnh) {
  const int s    = blockIdx.x >> 6;
  const int tile = blockIdx.x & 63;
  const int tid  = threadIdx.x;
  const int rg   = tid >> 6;
  const int ce   = tid & 63;
  __shared__ float As[32][DD];
  const int m0 = tile * 32;
  {
    const float4* src = (const float4*)(ctx + (size_t)m0 * DD);
    float4* dst = (float4*)&As[0][0];
#pragma unroll
    for (int i = 0; i < 8; ++i) dst[tid + i * 256] = src[tid + i * 256];
  }
  __syncthreads();
  const float* Wp = W + (size_t)s * DD * DD + (size_t)(ce * 4) * DD;
  float acc[8][4];
#pragma unroll
  for (int i = 0; i < 8; ++i)
#pragma unroll
    for (int j = 0; j < 4; ++j) acc[i][j] = 0.f;

  for (int d4 = 0; d4 < 64; ++d4) {
    const float4 w0 = *(const float4*)(Wp + 0 * DD + d4 * 4);
    const float4 w1 = *(const float4*)(Wp + 1 * DD + d4 * 4);
    const float4 w2 = *(const float4*)(Wp + 2 * DD + d4 * 4);
    const float4 w3 = *(const float4*)(Wp + 3 * DD + d4 * 4);
#pragma unroll
    for (int i = 0; i < 8; ++i) {
      const float4 a = *(const float4*)&As[rg * 8 + i][d4 * 4];
      acc[i][0] += a.x * w0.x + a.y * w0.y + a.z * w0.z + a.w * w0.w;
      acc[i][1] += a.x * w1.x + a.y * w1.y + a.z * w1.z + a.w * w1.w;
      acc[i][2] += a.x * w2.x + a.y * w2.y + a.z * w2.z + a.w * w2.w;
      acc[i][3] += a.x * w3.x + a.y * w3.y + a.z * w3.z + a.w * w3.w;
    }
  }
  const float4 bv = *(const float4*)(bias + (size_t)s * DD + ce * 4);
#pragma unroll
  for (int i = 0; i < 8; ++i) {
    acc[i][0] += bv.x; acc[i][1] += bv.y; acc[i][2] += bv.z; acc[i][3] += bv.w;
    float ss = acc[i][0]*acc[i][0] + acc[i][1]*acc[i][1]
             + acc[i][2]*acc[i][2] + acc[i][3]*acc[i][3];
#pragma unroll
    for (int off = 1; off < 64; off <<= 1) ss += __shfl_xor(ss, off, 64);
    const float scale = 1.0f / fmaxf(sqrtf(ss), 1e-12f);
    const int m = m0 + rg * 8 + i;
    union { _Float16 h[4]; uint2 u; } o;
    o.h[0] = (_Float16)(acc[i][0] * scale); o.h[1] = (_Float16)(acc[i][1] * scale);
    o.h[2] = (_Float16)(acc[i][2] * scale); o.h[3] = (_Float16)(acc[i][3] * scale);
    ((uint2*)(qnh + (((size_t)s * (BB * TT)) + m) * DD))[ce] = o.u;
  }
}

// ------------- scoring: 16-lane f16 dot groups + log-softmax -------------
__global__ __launch_bounds__(128) void score_kernel(const _Float16* __restrict__ qnh,
                                                    const _Float16* __restrict__ tnh,
                                                    const int* __restrict__ idx,
                                                    float* __restrict__ partial) {
  const int t    = blockIdx.x;            // 0..254
  const int b    = blockIdx.y;
  const int si   = blockIdx.z;
  const int step = si + 1;
  const int T2   = TT - step;
  const int lin  = (si * BB + b) * 255 + t;
  const int tid  = threadIdx.x;
  if (t >= T2) { if (tid == 0) partial[lin] = 0.f; return; }

  __shared__ int   rowIdx[NNEG + 1];
  __shared__ float logit[NNEG + 1];

  if (tid < NNEG) {
    rowIdx[tid + 1] = idx[((si * BB + b) * 255 + t) * NNEG + tid];
  } else if (tid == NNEG) {
    rowIdx[0] = b * TT + t + step;        // positive row
  }

  const int g  = tid >> 4;                // dot-group 0..7
  const int sl = tid & 15;                // 16 lanes per dot, 16 halves each
  const uint4* qrow = (const uint4*)(qnh + (((size_t)si * (BB * TT)) + b * TT + t) * DD);
  V16 qa, qb;
  qa.u = qrow[sl * 2]; qb.u = qrow[sl * 2 + 1];
  __syncthreads();

#pragma unroll
  for (int it = 0; it < 13; ++it) {
    const int k = it * 8 + g;
    if (k <= NNEG) {
      const uint4* p = (const uint4*)(tnh + (size_t)rowIdx[k] * DD);
      V16 pa, pb;
      pa.u = p[sl * 2]; pb.u = p[sl * 2 + 1];
      float d = 0.f;
#pragma unroll
      for (int j = 0; j < 4; ++j) d = fdot2(qa.h[j], pa.h[j], d);
#pragma unroll
      for (int j = 0; j < 4; ++j) d = fdot2(qb.h[j], pb.h[j], d);
#pragma unroll
      for (int off = 1; off < 16; off <<= 1) d += __shfl_xor(d, off, 64);
      if (sl == 0) logit[k] = d * 10.0f;  // 1/TEMP
    }
  }
  __syncthreads();

  if (tid < 64) {
    const int lane = tid;
    const float a = logit[lane];
    const float c = (lane + 64 <= NNEG) ? logit[lane + 64] : -1e30f;
    float m = fmaxf(a, c);
#pragma unroll
    for (int off = 1; off < 64; off <<= 1) m = fmaxf(m, __shfl_xor(m, off, 64));
    float e = __expf(a - m) + ((lane + 64 <= NNEG) ? __expf(c - m) : 0.f);
#pragma unroll
    for (int off = 1; off < 64; off <<= 1) e += __shfl_xor(e, off, 64);
    if (lane == 0) {
      const float lse = m + logf(e);
      partial[lin] = (lse - logit[0]) / (12.0f * (float)(BB * T2));
    }
  }
}

// ---------------- final reduction ----------------
__global__ __launch_bounds__(256) void final_sum_kernel(const float* __restrict__ partial,
                                                        float* __restrict__ out) {
  __shared__ float wsum[4];
  const int tid = threadIdx.x;
  float s = 0.f;
  const float4* p4 = (const float4*)partial;
  for (int i = tid; i < NPART / 4; i += 256) {
    const float4 v = p4[i];
    s += v.x + v.y + v.z + v.w;
  }
#pragma unroll
  for (int off = 1; off < 64; off <<= 1) s += __shfl_xor(s, off, 64);
  if ((tid & 63) == 0) wsum[tid >> 6] = s;
  __syncthreads();
  if (tid == 0) out[0] = wsum[0] + wsum[1] + wsum[2] + wsum[3];
}

extern "C" void kernel_launch(void* const* d_in, const int* in_sizes, int n_in,
                              void* d_out, int out_size, void* d_ws, size_t ws_size,
                              hipStream_t stream) {
  const float* ctx  = (const float*)d_in[0];
  const float* tgt  = (const float*)d_in[1];
  const float* W    = (const float*)d_in[2];
  const float* bias = (const float*)d_in[3];
  float* out = (float*)d_out;

  _Float16* tnh = (_Float16*)d_ws;                       // 2048*256 f16 (1 MB)
  _Float16* qnh = tnh + (size_t)BB * TT * DD;            // 12*2048*256 f16 (12.6 MB)
  uint4* keys   = (uint4*)(qnh + (size_t)NSTEP * BB * TT * DD); // 12 * 16B
  int* idx      = (int*)(keys + NSTEP);                  // 12*8*255*100 int (9.8 MB)
  float* partial = (float*)(idx + (size_t)NSTEP * BB * 255 * NNEG); // NPART f32

  hipLaunchKernelGGL(tnorm_keys_kernel, dim3((BB * TT) / 4), dim3(256), 0, stream,
                     tgt, tnh, keys);
  hipLaunchKernelGGL(idx_gen_kernel, dim3(100, BB, NSTEP), dim3(256), 0, stream,
                     keys, idx);
  hipLaunchKernelGGL(qgemm_kernel, dim3(NSTEP * 64), dim3(256), 0, stream,
                     ctx, W, bias, qnh);
  hipLaunchKernelGGL(score_kernel, dim3(255, BB, NSTEP), dim3(128), 0, stream,
                     qnh, tnh, idx, partial);
  hipLaunchKernelGGL(final_sum_kernel, dim3(1), dim3(256), 0, stream, partial, out);
}

// Round 3
// 169.588 us; speedup vs baseline: 2.4742x; 1.5243x over previous
//
#include <hip/hip_runtime.h>
#include <stdint.h>

#define BB 8
#define TT 256
#define DD 256
#define NSTEP 12
#define NNEG 100
#define NPART (255 * BB * NSTEP)

typedef _Float16 h2 __attribute__((ext_vector_type(2)));
typedef _Float16 f16x8 __attribute__((ext_vector_type(8)));
typedef float f32x4 __attribute__((ext_vector_type(4)));

#if __has_builtin(__builtin_amdgcn_fdot2)
__device__ __forceinline__ float fdot2(h2 a, h2 b, float c) {
  return __builtin_amdgcn_fdot2(a, b, c, false);
}
#else
__device__ __forceinline__ float fdot2(h2 a, h2 b, float c) {
  return c + (float)a.x * (float)b.x + (float)a.y * (float)b.y;
}
#endif

union V16 { uint4 u; h2 h[4]; };

// ---------------- Threefry2x32 (JAX-compatible) ----------------
__device__ __forceinline__ void tf2x32(uint32_t k0, uint32_t k1,
                                       uint32_t x0, uint32_t x1,
                                       uint32_t &y0, uint32_t &y1) {
  const uint32_t ks2 = k0 ^ k1 ^ 0x1BD11BDAu;
  x0 += k0; x1 += k1;
#define TF_R(r) { x0 += x1; x1 = (x1 << (r)) | (x1 >> (32 - (r))); x1 ^= x0; }
  TF_R(13) TF_R(15) TF_R(26) TF_R(6)
  x0 += k1; x1 += ks2 + 1u;
  TF_R(17) TF_R(29) TF_R(16) TF_R(24)
  x0 += ks2; x1 += k0 + 2u;
  TF_R(13) TF_R(15) TF_R(26) TF_R(6)
  x0 += k0; x1 += k1 + 3u;
  TF_R(17) TF_R(29) TF_R(16) TF_R(24)
  x0 += k1; x1 += ks2 + 4u;
  TF_R(13) TF_R(15) TF_R(26) TF_R(6)
  x0 += ks2; x1 += k0 + 5u;
#undef TF_R
  y0 = x0; y1 = x1;
}

// ------------- prep: tgt-l2norm->f16, ctx->f16, W->f16, step keys -------------
// blocks 0..511: tgt rows (norm). blocks 512..1023: ctx rows. 1024..1791: W rows.
__global__ __launch_bounds__(256) void prep_kernel(const float* __restrict__ tgt,
                                                   const float* __restrict__ ctx,
                                                   const float* __restrict__ W,
                                                   _Float16* __restrict__ tnh,
                                                   _Float16* __restrict__ ctxh,
                                                   _Float16* __restrict__ Wh,
                                                   uint4* __restrict__ keys) {
  const int bx = blockIdx.x;
  const int tid = threadIdx.x;
  if (bx == 0 && tid < NSTEP) {
    const int s = tid;
    uint32_t a, b;
    tf2x32(0u, 1234u, 0u, (uint32_t)(s + 1), a, b);     // fold_in(key(1234), step)
    uint32_t h1a, h1b, h2a, h2b;
    tf2x32(a, b, 0u, 2u, h1a, h1b);                     // split -> k1
    tf2x32(a, b, 1u, 3u, h2a, h2b);                     // split -> k2
    keys[s] = make_uint4(h1a, h2a, h1b, h2b);
  }
  const int lane = tid & 63;
  union { _Float16 h[4]; uint2 u; } o;
  if (bx < 512) {                                        // tgt: normalize
    const int row = bx * 4 + (tid >> 6);
    float4 v = ((const float4*)(tgt + (size_t)row * DD))[lane];
    float ss = v.x*v.x + v.y*v.y + v.z*v.z + v.w*v.w;
#pragma unroll
    for (int off = 1; off < 64; off <<= 1) ss += __shfl_xor(ss, off, 64);
    const float sc = 1.0f / fmaxf(sqrtf(ss), 1e-12f);
    o.h[0] = (_Float16)(v.x * sc); o.h[1] = (_Float16)(v.y * sc);
    o.h[2] = (_Float16)(v.z * sc); o.h[3] = (_Float16)(v.w * sc);
    ((uint2*)(tnh + (size_t)row * DD))[lane] = o.u;
  } else if (bx < 1024) {                                // ctx: plain convert
    const int row = (bx - 512) * 4 + (tid >> 6);
    float4 v = ((const float4*)(ctx + (size_t)row * DD))[lane];
    o.h[0] = (_Float16)v.x; o.h[1] = (_Float16)v.y;
    o.h[2] = (_Float16)v.z; o.h[3] = (_Float16)v.w;
    ((uint2*)(ctxh + (size_t)row * DD))[lane] = o.u;
  } else {                                               // W: plain convert (3072 rows)
    const int row = (bx - 1024) * 4 + (tid >> 6);
    float4 v = ((const float4*)(W + (size_t)row * DD))[lane];
    o.h[0] = (_Float16)v.x; o.h[1] = (_Float16)v.y;
    o.h[2] = (_Float16)v.z; o.h[3] = (_Float16)v.w;
    ((uint2*)(Wh + (size_t)row * DD))[lane] = o.u;
  }
}

// ------------- negative-index generation (threefry + mod) -> uint16 rows -------------
__global__ __launch_bounds__(256) void idx_gen_kernel(const uint4* __restrict__ keys,
                                                      uint16_t* __restrict__ idx) {
  const int si = blockIdx.z;
  const int b  = blockIdx.y;
  const int lin = blockIdx.x * 256 + threadIdx.x;
  if (lin >= 255 * NNEG) return;
  const int t = lin / NNEG;
  const int k = lin - t * NNEG;
  const int step = si + 1;
  const int T2 = TT - step;
  if (t >= T2) return;
  const uint4 kk = keys[si];
  const uint32_t span = (uint32_t)(BB * T2);
  const uint32_t j = (uint32_t)((b * T2 + t) * NNEG + k);
  uint32_t h0, h1, l0, l1;
  tf2x32(kk.x, kk.y, 0u, j, h0, h1);
  tf2x32(kk.z, kk.w, 0u, j, l0, l1);
  uint32_t mult = 65536u % span;
  mult = (mult * mult) % span;
  const uint32_t off = ((h0 % span) * mult + (l0 % span)) % span;
  const uint32_t bb = off / (uint32_t)T2;
  const uint32_t tt = off - bb * (uint32_t)T2;
  idx[((si * BB + b) * 255 + t) * NNEG + k] = (uint16_t)(bb * TT + tt + (uint32_t)step);
}

// ------------- query GEMM (MFMA f16) + bias + l2norm -> f16 -------------
// grid (128 m-tiles of 16 rows, 12 steps), block 256 = 4 waves.
// wave w owns cols [w*64, w*64+64) as 4 16x16 accumulators; K=256 in 8 MFMA steps.
__global__ __launch_bounds__(256) void qgemm_mfma_kernel(const _Float16* __restrict__ ctxh,
                                                         const _Float16* __restrict__ Wh,
                                                         const float* __restrict__ bias,
                                                         _Float16* __restrict__ qnh) {
  const int mt  = blockIdx.x;           // 0..127
  const int s   = blockIdx.y;           // 0..11
  const int tid = threadIdx.x;
  const int w   = tid >> 6;             // wave -> n0 = w*64
  const int lane = tid & 63;
  const int sl = lane & 15;             // fragment row/col index
  const int q  = lane >> 4;             // k-quad
  const int m0 = mt * 16;

  const _Float16* Arow  = ctxh + ((size_t)(m0 + sl)) * DD + q * 8;
  const _Float16* Bbase = Wh + (size_t)s * DD * DD + ((size_t)(w * 64 + sl)) * DD + q * 8;

  f32x4 acc[4] = {f32x4{0,0,0,0}, f32x4{0,0,0,0}, f32x4{0,0,0,0}, f32x4{0,0,0,0}};
#pragma unroll
  for (int k0 = 0; k0 < 8; ++k0) {
    const f16x8 a = *(const f16x8*)(Arow + k0 * 32);
#pragma unroll
    for (int nt = 0; nt < 4; ++nt) {
      const f16x8 b = *(const f16x8*)(Bbase + (size_t)nt * 16 * DD + k0 * 32);
      acc[nt] = __builtin_amdgcn_mfma_f32_16x16x32_f16(a, b, acc[nt], 0, 0, 0);
    }
  }
  // bias: col = w*64 + nt*16 + sl; row = q*4 + reg
  const float* bp = bias + (size_t)s * DD + w * 64 + sl;
#pragma unroll
  for (int nt = 0; nt < 4; ++nt) {
    const float bv = bp[nt * 16];
#pragma unroll
    for (int r = 0; r < 4; ++r) acc[nt][r] += bv;
  }
  // per-row sum of squares: this wave's 64-col partial, rows q*4+reg
  float ss[4];
#pragma unroll
  for (int r = 0; r < 4; ++r) {
    float v = 0.f;
#pragma unroll
    for (int nt = 0; nt < 4; ++nt) v += acc[nt][r] * acc[nt][r];
    ss[r] = v;
  }
#pragma unroll
  for (int off = 1; off < 16; off <<= 1) {
#pragma unroll
    for (int r = 0; r < 4; ++r) ss[r] += __shfl_xor(ss[r], off, 64);
  }
  __shared__ float part[4][16];
  if (sl == 0) {
#pragma unroll
    for (int r = 0; r < 4; ++r) part[w][q * 4 + r] = ss[r];
  }
  __syncthreads();
#pragma unroll
  for (int r = 0; r < 4; ++r) {
    const int row = q * 4 + r;
    const float tot = part[0][row] + part[1][row] + part[2][row] + part[3][row];
    const float sc = 1.0f / fmaxf(sqrtf(tot), 1e-12f);
    _Float16* outp = qnh + (((size_t)s * (BB * TT)) + m0 + row) * DD + w * 64 + sl;
#pragma unroll
    for (int nt = 0; nt < 4; ++nt) outp[nt * 16] = (_Float16)(acc[nt][r] * sc);
  }
}

// ------------- scoring: 16-lane f16 dot groups + log-softmax -------------
__global__ __launch_bounds__(128) void score_kernel(const _Float16* __restrict__ qnh,
                                                    const _Float16* __restrict__ tnh,
                                                    const uint16_t* __restrict__ idx,
                                                    float* __restrict__ partial) {
  const int t    = blockIdx.x;            // 0..254
  const int b    = blockIdx.y;
  const int si   = blockIdx.z;
  const int step = si + 1;
  const int T2   = TT - step;
  const int lin  = (si * BB + b) * 255 + t;
  const int tid  = threadIdx.x;
  if (t >= T2) { if (tid == 0) partial[lin] = 0.f; return; }

  __shared__ int   rowIdx[NNEG + 1];
  __shared__ float logit[NNEG + 1];

  if (tid < NNEG) {
    rowIdx[tid + 1] = (int)idx[((si * BB + b) * 255 + t) * NNEG + tid];
  } else if (tid == NNEG) {
    rowIdx[0] = b * TT + t + step;        // positive row
  }

  const int g  = tid >> 4;                // dot-group 0..7
  const int sl = tid & 15;                // 16 lanes per dot, 16 halves each
  const uint4* qrow = (const uint4*)(qnh + (((size_t)si * (BB * TT)) + b * TT + t) * DD);
  V16 qa, qb;
  qa.u = qrow[sl * 2]; qb.u = qrow[sl * 2 + 1];
  __syncthreads();

#pragma unroll
  for (int it = 0; it < 13; ++it) {
    const int k = it * 8 + g;
    if (k <= NNEG) {
      const uint4* p = (const uint4*)(tnh + (size_t)rowIdx[k] * DD);
      V16 pa, pb;
      pa.u = p[sl * 2]; pb.u = p[sl * 2 + 1];
      float d0 = 0.f, d1 = 0.f;
#pragma unroll
      for (int j = 0; j < 4; ++j) d0 = fdot2(qa.h[j], pa.h[j], d0);
#pragma unroll
      for (int j = 0; j < 4; ++j) d1 = fdot2(qb.h[j], pb.h[j], d1);
      float d = d0 + d1;
#pragma unroll
      for (int off = 1; off < 16; off <<= 1) d += __shfl_xor(d, off, 64);
      if (sl == 0) logit[k] = d * 10.0f;  // 1/TEMP
    }
  }
  __syncthreads();

  if (tid < 64) {
    const int lane = tid;
    const float a = logit[lane];
    const float c = (lane + 64 <= NNEG) ? logit[lane + 64] : -1e30f;
    float m = fmaxf(a, c);
#pragma unroll
    for (int off = 1; off < 64; off <<= 1) m = fmaxf(m, __shfl_xor(m, off, 64));
    float e = __expf(a - m) + ((lane + 64 <= NNEG) ? __expf(c - m) : 0.f);
#pragma unroll
    for (int off = 1; off < 64; off <<= 1) e += __shfl_xor(e, off, 64);
    if (lane == 0) {
      const float lse = m + logf(e);
      partial[lin] = (lse - logit[0]) / (12.0f * (float)(BB * T2));
    }
  }
}

// ---------------- final reduction ----------------
__global__ __launch_bounds__(256) void final_sum_kernel(const float* __restrict__ partial,
                                                        float* __restrict__ out) {
  __shared__ float wsum[4];
  const int tid = threadIdx.x;
  float s = 0.f;
  const float4* p4 = (const float4*)partial;
  for (int i = tid; i < NPART / 4; i += 256) {
    const float4 v = p4[i];
    s += v.x + v.y + v.z + v.w;
  }
#pragma unroll
  for (int off = 1; off < 64; off <<= 1) s += __shfl_xor(s, off, 64);
  if ((tid & 63) == 0) wsum[tid >> 6] = s;
  __syncthreads();
  if (tid == 0) out[0] = wsum[0] + wsum[1] + wsum[2] + wsum[3];
}

extern "C" void kernel_launch(void* const* d_in, const int* in_sizes, int n_in,
                              void* d_out, int out_size, void* d_ws, size_t ws_size,
                              hipStream_t stream) {
  const float* ctx  = (const float*)d_in[0];
  const float* tgt  = (const float*)d_in[1];
  const float* W    = (const float*)d_in[2];
  const float* bias = (const float*)d_in[3];
  float* out = (float*)d_out;

  _Float16* tnh  = (_Float16*)d_ws;                          // 2048*256 f16 (1 MB)
  _Float16* ctxh = tnh + (size_t)BB * TT * DD;               // 2048*256 f16 (1 MB)
  _Float16* Wh   = ctxh + (size_t)BB * TT * DD;              // 12*256*256 f16 (1.5 MB)
  _Float16* qnh  = Wh + (size_t)NSTEP * DD * DD;             // 12*2048*256 f16 (12.6 MB)
  uint4* keys    = (uint4*)(qnh + (size_t)NSTEP * BB * TT * DD); // 12 * 16B
  uint16_t* idx  = (uint16_t*)(keys + NSTEP);                // 12*8*255*100 u16 (4.9 MB)
  float* partial = (float*)(idx + (size_t)NSTEP * BB * 255 * NNEG); // NPART f32

  hipLaunchKernelGGL(prep_kernel, dim3(1792), dim3(256), 0, stream,
                     tgt, ctx, W, tnh, ctxh, Wh, keys);
  hipLaunchKernelGGL(idx_gen_kernel, dim3(100, BB, NSTEP), dim3(256), 0, stream,
                     keys, idx);
  hipLaunchKernelGGL(qgemm_mfma_kernel, dim3(128, NSTEP), dim3(256), 0, stream,
                     ctxh, Wh, bias, qnh);
  hipLaunchKernelGGL(score_kernel, dim3(255, BB, NSTEP), dim3(128), 0, stream,
                     qnh, tnh, idx, partial);
  hipLaunchKernelGGL(final_sum_kernel, dim3(1), dim3(256), 0, stream, partial, out);
}